// Round 5
// baseline (594.566 us; speedup 1.0000x reference)
//
#include <hip/hip_runtime.h>
#include <hip/hip_bf16.h>
#include <math.h>

typedef __hip_bfloat16 bf16;
typedef __attribute__((ext_vector_type(8))) short short8;
typedef __attribute__((ext_vector_type(4))) float floatx4;

#define EMB   1024
#define SEQ   2048
#define BATCH 4
#define M_TOK 8192
#define HEADS 16
#define HDIM  64
#define FFDIM 4096
#define KVB   64

typedef __attribute__((address_space(3))) void lds_t;
typedef __attribute__((address_space(1))) void glob_t;

static __device__ __forceinline__ void gll16(const bf16* g, bf16* l) {
  __builtin_amdgcn_global_load_lds((const glob_t*)g, (lds_t*)l, 16, 0, 0);
}

template<int N>
static __device__ __forceinline__ void wait_vmcnt() {
  asm volatile("s_waitcnt vmcnt(%0)" :: "n"(N) : "memory");
}

static __device__ __forceinline__ unsigned short f2bu(float f) {
  union { __hip_bfloat16 h; unsigned short u; } cv;
  cv.h = __float2bfloat16(f);
  return cv.u;
}

static __device__ __forceinline__ float gelu_f(float x) {
  float t = tanhf(0.7978845608028654f * (x + 0.044715f * x * x * x));
  return 0.5f * x * (1.0f + t);
}

// ---- weight convert + transpose: W fp32 [Kd][Nd] -> Wt bf16 [Nd][Kd] ----
__global__ __launch_bounds__(256) void wconv_kernel(const float* __restrict__ W,
                                                    bf16* __restrict__ Wt,
                                                    int Kd, int Nd) {
  __shared__ float tile[32][33];
  int n0 = blockIdx.x * 32, k0 = blockIdx.y * 32;
  int tx = threadIdx.x & 31, ty = threadIdx.x >> 5;
  #pragma unroll
  for (int j = 0; j < 32; j += 8)
    tile[ty + j][tx] = W[(size_t)(k0 + ty + j) * Nd + n0 + tx];
  __syncthreads();
  #pragma unroll
  for (int j = 0; j < 32; j += 8)
    Wt[(size_t)(n0 + ty + j) * Kd + k0 + tx] = __float2bfloat16(tile[tx][ty + j]);
}

// ---- LayerNorm (ddof=1): fp32 [8192][1024] -> bf16 ----
__global__ __launch_bounds__(256) void ln_kernel(const float* __restrict__ x,
                                                 const float* __restrict__ sc,
                                                 const float* __restrict__ bi,
                                                 bf16* __restrict__ out) {
  int row = blockIdx.x, tid = threadIdx.x;
  const float4* xr = (const float4*)(x + (size_t)row * EMB);
  float4 v = xr[tid];
  float s  = v.x + v.y + v.z + v.w;
  float s2 = v.x * v.x + v.y * v.y + v.z * v.z + v.w * v.w;
  #pragma unroll
  for (int off = 1; off < 64; off <<= 1) {
    s  += __shfl_xor(s, off);
    s2 += __shfl_xor(s2, off);
  }
  __shared__ float red[8];
  int wv = tid >> 6;
  if ((tid & 63) == 0) { red[wv] = s; red[4 + wv] = s2; }
  __syncthreads();
  s  = red[0] + red[1] + red[2] + red[3];
  s2 = red[4] + red[5] + red[6] + red[7];
  float mean = s * (1.0f / EMB);
  float var  = (s2 - (float)EMB * mean * mean) * (1.0f / (EMB - 1));
  float rstd = rsqrtf(var + 1e-5f);
  float4 scv = ((const float4*)sc)[tid];
  float4 biv = ((const float4*)bi)[tid];
  ushort4 o;
  o.x = f2bu((v.x - mean) * rstd * scv.x + biv.x);
  o.y = f2bu((v.y - mean) * rstd * scv.y + biv.y);
  o.z = f2bu((v.z - mean) * rstd * scv.z + biv.z);
  o.w = f2bu((v.w - mean) * rstd * scv.w + biv.w);
  ((ushort4*)(out + (size_t)row * EMB))[tid] = o;
}

// ---- 256-tile 4-quadrant-phase GEMM (m201 schedule): C = A[M][Kd]*Bt[N][Kd]^T
// 512 thr = 8 waves (2M x 4N), BK=64. Staging in consumption order
// (A0,B0,B1,A1), one half-tile per phase, per-phase FIFO-derived counted
// vmcnt (steady 6/6/6 for BN=256, 5/5/4 for BN=128; epilogue 4/2/0) so every
// half has 3-4 phases of flight. Reads post-barrier; swizzle rule 21.
// MODE 3: fp32 out = C+bias+resid   MODE 4: bf16 out = gelu(C+bias)
// MODE 6: fused QKV scatter, n in [0,3072): z=n>>10 (0=q scaled,1=k,2=vT)
template<int BN, int Kd, int MODE>
__global__ __launch_bounds__(512, 1) void gemm8_kernel(
    const bf16* __restrict__ A, const bf16* __restrict__ Bt,
    const float* __restrict__ bias, const float* __restrict__ resid,
    void* __restrict__ outp) {
  constexpr int BM = 256, BK = 64;
  constexpr int MR = 8, MRh = 4;
  constexpr int NR = BN / 64, NRh = NR / 2;      // 4/2 or 2/1
  constexpr int BL = BN / 128;                   // gloads per B half (2 or 1)
  constexpr int NT = Kd / BK;

  __shared__ __align__(16) bf16 As[2][2][128 * 64];
  __shared__ __align__(16) bf16 Bs[2][2][(BN / 2) * 64];

  const int tid = threadIdx.x;
  const int lane = tid & 63, wave = tid >> 6;
  const int lo = lane & 15, hi = lane >> 4, lo7 = lane & 7;
  const int wm = wave >> 2, wn = wave & 3;
  const int m0 = blockIdx.x * BM, n0 = blockIdx.y * BN;

  const bf16* Ag = A  + (size_t)m0 * Kd;
  const bf16* Bg = Bt + (size_t)n0 * Kd;

  // A half h = row bands {h*64..h*64+63} and {128+h*64..}: quadrant mh of both
  // wave-M groups. Chunks linear in LDS; source col pre-swizzled by row&7.
  auto SA = [&](int h, int b, int kt) {
    #pragma unroll
    for (int l = 0; l < 2; l++) {
      const int ch = l * 512 + tid;
      const int r = (ch >> 3) & 63;
      const int row = ((ch >> 9) << 7) + h * 64 + r;
      const int slot = (ch & 7) ^ (r & 7);
      gll16(Ag + (size_t)row * Kd + kt * BK + slot * 8, &As[b][h][0] + ch * 8);
    }
  };
  // B half h = per-wave-group bands of BN/8 rows.
  auto SB = [&](int h, int b, int kt) {
    #pragma unroll
    for (int l = 0; l < BL; l++) {
      const int ch = l * 512 + tid;
      int row, r;
      if constexpr (BN == 256) { r = (ch >> 3) & 31; row = ((ch >> 8) << 6) + h * 32 + r; }
      else                     { r = (ch >> 3) & 15; row = ((ch >> 7) << 5) + h * 16 + r; }
      const int slot = (ch & 7) ^ (r & 7);
      gll16(Bg + (size_t)row * Kd + kt * BK + slot * 8, &Bs[b][h][0] + ch * 8);
    }
  };

  auto RA = [&](int h, int b, short8 (&af)[MRh][2]) {
    #pragma unroll
    for (int i = 0; i < MRh; i++)
      #pragma unroll
      for (int kk = 0; kk < 2; kk++)
        af[i][kk] = *(const short8*)&As[b][h][(wm * 64 + i * 16 + lo) * 64 +
                                             (((kk * 4 + hi) ^ lo7) * 8)];
  };
  auto RB = [&](int h, int b, short8 (&bf)[NRh][2]) {
    #pragma unroll
    for (int j = 0; j < NRh; j++)
      #pragma unroll
      for (int kk = 0; kk < 2; kk++)
        bf[j][kk] = *(const short8*)&Bs[b][h][(wn * (BN / 8) + j * 16 + lo) * 64 +
                                              (((kk * 4 + hi) ^ lo7) * 8)];
  };

  floatx4 acc[MR][NR];
  #pragma unroll
  for (int i = 0; i < MR; i++)
    #pragma unroll
    for (int j = 0; j < NR; j++)
      #pragma unroll
      for (int r = 0; r < 4; r++) acc[i][j][r] = 0.0f;

  short8 af[MRh][2], bf0[NRh][2], bf1[NRh][2];

  auto MM = [&](int mh, int nh, short8 (&a)[MRh][2], short8 (&bb)[NRh][2]) {
    __builtin_amdgcn_s_setprio(1);
    #pragma unroll
    for (int kk = 0; kk < 2; kk++)
      #pragma unroll
      for (int i = 0; i < MRh; i++)
        #pragma unroll
        for (int j = 0; j < NRh; j++)
          acc[mh * MRh + i][nh * NRh + j] = __builtin_amdgcn_mfma_f32_16x16x32_bf16(
              a[i][kk], bb[j][kk], acc[mh * MRh + i][nh * NRh + j], 0, 0, 0);
    __builtin_amdgcn_s_setprio(0);
  };
  auto BAR = [&]() {
    __builtin_amdgcn_s_barrier();
    __builtin_amdgcn_sched_barrier(0);
  };

  // prologue: stage tile 0 fully, in consumption order A0,B0,B1,A1
  SA(0, 0, 0); SB(0, 0, 0); SB(1, 0, 0); SA(1, 0, 0);

  for (int t = 0; t < NT; ++t) {
    const int b = t & 1, bn = b ^ 1;
    const bool L = (t + 1 == NT);
    // ---- p0: quadrant (m0,n0); stage A0(t+1). Need A0,B0 of t landed;
    //      allow B1(t)+A1(t)+A0(t+1) outstanding -> vmcnt(BL+4) steady.
    if (!L) { SA(0, bn, t + 1); wait_vmcnt<BL + 4>(); }
    else    { wait_vmcnt<BL + 2>(); }
    BAR();
    RA(0, b, af); RB(0, b, bf0);
    MM(0, 0, af, bf0);
    BAR();
    // ---- p1: (m0,n1); stage B0(t+1). Need B1(t); allow A1+A0'+B0'.
    if (!L) { SB(0, bn, t + 1); wait_vmcnt<4 + BL>(); }
    else    { wait_vmcnt<2>(); }
    BAR();
    RB(1, b, bf1);
    MM(0, 1, af, bf1);
    BAR();
    // ---- p2: (m1,n1); stage B1(t+1). Need A1(t); allow A0'+B0'+B1'.
    if (!L) { SB(1, bn, t + 1); wait_vmcnt<2 + 2 * BL>(); }
    else    { wait_vmcnt<0>(); }
    BAR();
    RA(1, b, af);
    MM(1, 1, af, bf1);
    BAR();
    // ---- p3: (m1,n0); stage A1(t+1). No new data needed.
    if (!L) SA(1, bn, t + 1);
    BAR();
    MM(1, 0, af, bf0);
    BAR();
  }

  #pragma unroll
  for (int ri = 0; ri < MR; ri++) {
    const int mb = m0 + wm * 128 + (ri >> 2) * 64 + (ri & 3) * 16 + hi * 4;
    #pragma unroll
    for (int cj = 0; cj < NR; cj++) {
      const int n = n0 + wn * (BN / 4) + (cj / NRh) * (BN / 8) + (cj % NRh) * 16 + lo;
      if constexpr (MODE == 6) {
        const int z = n >> 10, nz = n & 1023;
        const int bx = mb >> 11, hhh = nz >> 6, d = nz & 63;
        bf16* ob = (bf16*)outp + ((size_t)z << 23);
        if (z == 2) {
          ushort4 pk;
          pk.x = f2bu(acc[ri][cj][0]); pk.y = f2bu(acc[ri][cj][1]);
          pk.z = f2bu(acc[ri][cj][2]); pk.w = f2bu(acc[ri][cj][3]);
          *(ushort4*)&ob[((size_t)(bx * HEADS + hhh) * HDIM + d) * SEQ + (mb & 2047)] = pk;
        } else {
          const float sc = (z == 0) ? 0.125f : 1.0f;
          #pragma unroll
          for (int r = 0; r < 4; r++) {
            const int ss = (mb + r) & 2047;
            ob[((size_t)(bx * HEADS + hhh) * SEQ + ss) * HDIM + d] =
                __float2bfloat16(acc[ri][cj][r] * sc);
          }
        }
      } else if constexpr (MODE == 3) {
        #pragma unroll
        for (int r = 0; r < 4; r++) {
          const int m = mb + r;
          ((float*)outp)[(size_t)m * EMB + n] =
              acc[ri][cj][r] + bias[n] + resid[(size_t)m * EMB + n];
        }
      } else if constexpr (MODE == 4) {
        #pragma unroll
        for (int r = 0; r < 4; r++)
          ((bf16*)outp)[(size_t)(mb + r) * FFDIM + n] =
              __float2bfloat16(gelu_f(acc[ri][cj][r] + bias[n]));
      }
    }
  }
}

// ---- causal flash attention, staged + double-buffered (round-2 + T5) ----
__global__ __launch_bounds__(256, 2) void attn_kernel(
    const bf16* __restrict__ q, const bf16* __restrict__ k,
    const bf16* __restrict__ vt, bf16* __restrict__ ctx) {
  __shared__ __align__(16) char KVs[2][2][64 * 128];
  __shared__ __align__(16) char Pls[4][4096];
  const int bh = blockIdx.x, qt = blockIdx.y;
  const int tid = threadIdx.x;
  const int wave = tid >> 6, lane = tid & 63;
  const int lo = lane & 15, hi = lane >> 4;
  const int lo7 = lo & 7;
  const int q0 = qt * 128;
  const int q0w = q0 + wave * 32;
  const int qmax = q0w + 31;

  const bf16* qp = q  + ((size_t)bh * SEQ + q0w) * HDIM;
  const bf16* kp = k  + (size_t)bh * SEQ * HDIM;
  const bf16* vp = vt + (size_t)bh * HDIM * SEQ;

  short8 qf[2][2];
  #pragma unroll
  for (int m = 0; m < 2; m++)
    #pragma unroll
    for (int kk = 0; kk < 2; kk++)
      qf[m][kk] = *(const short8*)&qp[(size_t)(m * 16 + lo) * HDIM + kk * 32 + hi * 8];

  float m_run[2] = {-1e30f, -1e30f};
  float l_run[2] = {0.0f, 0.0f};
  floatx4 o[4][2];
  #pragma unroll
  for (int df = 0; df < 4; df++)
    #pragma unroll
    for (int m = 0; m < 2; m++)
      #pragma unroll
      for (int r = 0; r < 4; r++) o[df][m][r] = 0.0f;

  const int nt = 2 * qt + 2;

  const int c0 = tid, c1 = tid + 256;
  const int r0 = c0 >> 3, s0 = (c0 & 7) ^ (r0 & 7);
  const int r1 = c1 >> 3, s1 = (c1 & 7) ^ (r1 & 7);

  gll16(kp + (size_t)r0 * HDIM + s0 * 8, (bf16*)&KVs[0][0][c0 * 16]);
  gll16(vp + (size_t)r0 * SEQ + s0 * 8,  (bf16*)&KVs[0][1][c0 * 16]);
  gll16(kp + (size_t)r1 * HDIM + s1 * 8, (bf16*)&KVs[0][0][c1 * 16]);
  gll16(vp + (size_t)r1 * SEQ + s1 * 8,  (bf16*)&KVs[0][1][c1 * 16]);

  for (int t = 0; t < nt; ++t) {
    const int buf = t & 1;
    const int k0 = t * KVB;
    if (t + 1 < nt) {
      const int kn = k0 + KVB;
      gll16(kp + (size_t)(kn + r0) * HDIM + s0 * 8, (bf16*)&KVs[buf ^ 1][0][c0 * 16]);
      gll16(vp + (size_t)r0 * SEQ + kn + s0 * 8,    (bf16*)&KVs[buf ^ 1][1][c0 * 16]);
      gll16(kp + (size_t)(kn + r1) * HDIM + s1 * 8, (bf16*)&KVs[buf ^ 1][0][c1 * 16]);
      gll16(vp + (size_t)r1 * SEQ + kn + s1 * 8,    (bf16*)&KVs[buf ^ 1][1][c1 * 16]);
      asm volatile("s_waitcnt vmcnt(4)" ::: "memory");
    } else {
      asm volatile("s_waitcnt vmcnt(0)" ::: "memory");
    }
    __builtin_amdgcn_s_barrier();
    __builtin_amdgcn_sched_barrier(0);

    if (k0 <= qmax) {
      const char* Kb = KVs[buf][0];
      const char* Vb = KVs[buf][1];
      floatx4 sfr[4][2];
      __builtin_amdgcn_s_setprio(1);
      #pragma unroll
      for (int kf = 0; kf < 4; kf++) {
        const int rowb = (kf * 16 + lo) * 128;
        short8 kf0 = *(const short8*)(Kb + rowb + (( 0 + hi * 16) ^ (lo7 << 4)));
        short8 kf1 = *(const short8*)(Kb + rowb + ((64 + hi * 16) ^ (lo7 << 4)));
        #pragma unroll
        for (int m = 0; m < 2; m++) {
          floatx4 z = {0.0f, 0.0f, 0.0f, 0.0f};
          z = __builtin_amdgcn_mfma_f32_16x16x32_bf16(kf0, qf[m][0], z, 0, 0, 0);
          z = __builtin_amdgcn_mfma_f32_16x16x32_bf16(kf1, qf[m][1], z, 0, 0, 0);
          sfr[kf][m] = z;
        }
      }
      __builtin_amdgcn_s_setprio(0);
      if (k0 + KVB - 1 > q0w) {
        #pragma unroll
        for (int m = 0; m < 2; m++) {
          const int qg = q0w + m * 16 + lo;
          #pragma unroll
          for (int kf = 0; kf < 4; kf++)
            #pragma unroll
            for (int r = 0; r < 4; r++) {
              const int key = k0 + kf * 16 + hi * 4 + r;
              if (key > qg) sfr[kf][m][r] = -1e30f;
            }
        }
      }
      float alpha[2];
      #pragma unroll
      for (int m = 0; m < 2; m++) {
        float tmax = -1e30f;
        #pragma unroll
        for (int kf = 0; kf < 4; kf++)
          #pragma unroll
          for (int r = 0; r < 4; r++) tmax = fmaxf(tmax, sfr[kf][m][r]);
        tmax = fmaxf(tmax, __shfl_xor(tmax, 16));
        tmax = fmaxf(tmax, __shfl_xor(tmax, 32));
        const float mn = fmaxf(m_run[m], tmax);
        alpha[m] = __expf(m_run[m] - mn);
        m_run[m] = mn;
        float ps = 0.0f;
        const int prow = (m * 16 + lo) * 128;
        #pragma unroll
        for (int kf = 0; kf < 4; kf++) {
          float p0 = __expf(sfr[kf][m][0] - mn);
          float p1 = __expf(sfr[kf][m][1] - mn);
          float p2 = __expf(sfr[kf][m][2] - mn);
          float p3 = __expf(sfr[kf][m][3] - mn);
          ps += (p0 + p1) + (p2 + p3);
          ushort4 pk;
          pk.x = f2bu(p0); pk.y = f2bu(p1); pk.z = f2bu(p2); pk.w = f2bu(p3);
          *(ushort4*)(Pls[wave] + prow + ((kf * 32 + hi * 8) ^ (lo7 << 4))) = pk;
        }
        ps += __shfl_xor(ps, 16);
        ps += __shfl_xor(ps, 32);
        l_run[m] = l_run[m] * alpha[m] + ps;
      }
      asm volatile("s_waitcnt lgkmcnt(0)" ::: "memory");
      __builtin_amdgcn_sched_barrier(0);
      short8 pa[2][2];
      #pragma unroll
      for (int m = 0; m < 2; m++)
        #pragma unroll
        for (int kk2 = 0; kk2 < 2; kk2++)
          pa[m][kk2] = *(const short8*)(Pls[wave] + (m * 16 + lo) * 128 +
                                        ((kk2 * 64 + hi * 16) ^ (lo7 << 4)));
      float ar[2][4];
      #pragma unroll
      for (int m = 0; m < 2; m++)
        #pragma unroll
        for (int r = 0; r < 4; r++) ar[m][r] = __shfl(alpha[m], hi * 4 + r);
      #pragma unroll
      for (int df = 0; df < 4; df++)
        #pragma unroll
        for (int m = 0; m < 2; m++)
          #pragma unroll
          for (int r = 0; r < 4; r++) o[df][m][r] *= ar[m][r];
      __builtin_amdgcn_s_setprio(1);
      #pragma unroll
      for (int df = 0; df < 4; df++) {
        const int rowb = (df * 16 + lo) * 128;
        short8 vf0 = *(const short8*)(Vb + rowb + (( 0 + hi * 16) ^ (lo7 << 4)));
        short8 vf1 = *(const short8*)(Vb + rowb + ((64 + hi * 16) ^ (lo7 << 4)));
        #pragma unroll
        for (int m = 0; m < 2; m++) {
          o[df][m] = __builtin_amdgcn_mfma_f32_16x16x32_bf16(pa[m][0], vf0, o[df][m], 0, 0, 0);
          o[df][m] = __builtin_amdgcn_mfma_f32_16x16x32_bf16(pa[m][1], vf1, o[df][m], 0, 0, 0);
        }
      }
      __builtin_amdgcn_s_setprio(0);
    }
    __builtin_amdgcn_s_barrier();
    __builtin_amdgcn_sched_barrier(0);
  }

  const int b = bh >> 4, hh = bh & 15;
  #pragma unroll
  for (int m = 0; m < 2; m++) {
    float lr[4];
    #pragma unroll
    for (int r = 0; r < 4; r++) lr[r] = __shfl(l_run[m], hi * 4 + r);
    #pragma unroll
    for (int df = 0; df < 4; df++)
      #pragma unroll
      for (int r = 0; r < 4; r++) {
        const int srow = q0w + m * 16 + hi * 4 + r;
        ctx[((size_t)(b * SEQ + srow)) * EMB + hh * HDIM + df * 16 + lo] =
            __float2bfloat16(o[df][m][r] / lr[r]);
      }
  }
}

extern "C" void kernel_launch(void* const* d_in, const int* in_sizes, int n_in,
                              void* d_out, int out_size, void* d_ws, size_t ws_size,
                              hipStream_t stream) {
  const float* x   = (const float*)d_in[0];
  const float* Wq  = (const float*)d_in[1];
  const float* Wk  = (const float*)d_in[2];
  const float* Wv  = (const float*)d_in[3];
  const float* Wo  = (const float*)d_in[4];
  const float* bo  = (const float*)d_in[5];
  const float* l1s = (const float*)d_in[6];
  const float* l1b = (const float*)d_in[7];
  const float* l2s = (const float*)d_in[8];
  const float* l2b = (const float*)d_in[9];
  const float* W1  = (const float*)d_in[10];
  const float* b1  = (const float*)d_in[11];
  const float* W2  = (const float*)d_in[12];
  const float* b2  = (const float*)d_in[13];
  float* out = (float*)d_out;

  char* ws = (char*)d_ws;
  bf16* hbuf   = (bf16*)(ws);
  bf16* qbuf   = (bf16*)(ws + ((size_t)16 << 20));
  bf16* kbuf   = (bf16*)(ws + ((size_t)32 << 20));
  bf16* vbuf   = (bf16*)(ws + ((size_t)48 << 20));
  bf16* ctxbuf = hbuf;
  bf16* gbuf   = (bf16*)(ws);
  bf16* h2buf  = (bf16*)(ws + ((size_t)64 << 20));
  bf16* WqT    = (bf16*)(ws + ((size_t)80 << 20));
  bf16* WkT    = WqT + (1u << 20);
  bf16* WvT    = WkT + (1u << 20);
  bf16* WoT    = WvT + (1u << 20);
  bf16* W1T    = WoT + (1u << 20);
  bf16* W2T    = W1T + (4u << 20);

  wconv_kernel<<<dim3(32, 32), 256, 0, stream>>>(Wq, WqT, 1024, 1024);
  wconv_kernel<<<dim3(32, 32), 256, 0, stream>>>(Wk, WkT, 1024, 1024);
  wconv_kernel<<<dim3(32, 32), 256, 0, stream>>>(Wv, WvT, 1024, 1024);
  wconv_kernel<<<dim3(32, 32), 256, 0, stream>>>(Wo, WoT, 1024, 1024);
  wconv_kernel<<<dim3(128, 32), 256, 0, stream>>>(W1, W1T, 1024, 4096);
  wconv_kernel<<<dim3(32, 128), 256, 0, stream>>>(W2, W2T, 4096, 1024);

  ln_kernel<<<8192, 256, 0, stream>>>(x, l1s, l1b, hbuf);

  // fused QKV: Bt = [WqT;WkT;WvT] (3072 x 1024 contiguous), 256x256 tile
  gemm8_kernel<256, 1024, 6><<<dim3(32, 12), 512, 0, stream>>>(
      hbuf, WqT, nullptr, nullptr, qbuf);

  attn_kernel<<<dim3(64, 16), 256, 0, stream>>>(qbuf, kbuf, vbuf, ctxbuf);

  // Wo + bias + residual (fp32 out), 256x128 tile
  gemm8_kernel<128, 1024, 3><<<dim3(32, 8), 512, 0, stream>>>(
      ctxbuf, WoT, bo, x, (void*)out);
  ln_kernel<<<8192, 256, 0, stream>>>(out, l2s, l2b, h2buf);
  // FF1: 256x256 tile, gelu
  gemm8_kernel<256, 1024, 4><<<dim3(32, 16), 512, 0, stream>>>(
      h2buf, W1T, b1, nullptr, gbuf);
  // FF2: 256x128 tile, K=4096, bias + residual (fp32 out)
  gemm8_kernel<128, 4096, 3><<<dim3(32, 8), 512, 0, stream>>>(
      gbuf, W2T, b2, out, (void*)out);
}

// Round 6
// 519.121 us; speedup vs baseline: 1.1453x; 1.1453x over previous
//
#include <hip/hip_runtime.h>
#include <hip/hip_bf16.h>
#include <math.h>

typedef __hip_bfloat16 bf16;
typedef __attribute__((ext_vector_type(8))) short short8;
typedef __attribute__((ext_vector_type(4))) float floatx4;

#define EMB   1024
#define SEQ   2048
#define BATCH 4
#define M_TOK 8192
#define HEADS 16
#define HDIM  64
#define FFDIM 4096
#define KVB   64

typedef __attribute__((address_space(3))) void lds_t;
typedef __attribute__((address_space(1))) void glob_t;

static __device__ __forceinline__ void gll16(const bf16* g, bf16* l) {
  __builtin_amdgcn_global_load_lds((const glob_t*)g, (lds_t*)l, 16, 0, 0);
}

static __device__ __forceinline__ unsigned short f2bu(float f) {
  union { __hip_bfloat16 h; unsigned short u; } cv;
  cv.h = __float2bfloat16(f);
  return cv.u;
}

static __device__ __forceinline__ float gelu_f(float x) {
  float t = tanhf(0.7978845608028654f * (x + 0.044715f * x * x * x));
  return 0.5f * x * (1.0f + t);
}

// ---- weight convert + transpose: W fp32 [Kd][Nd] -> Wt bf16 [Nd][Kd] ----
__global__ __launch_bounds__(256) void wconv_kernel(const float* __restrict__ W,
                                                    bf16* __restrict__ Wt,
                                                    int Kd, int Nd) {
  __shared__ float tile[32][33];
  int n0 = blockIdx.x * 32, k0 = blockIdx.y * 32;
  int tx = threadIdx.x & 31, ty = threadIdx.x >> 5;
  #pragma unroll
  for (int j = 0; j < 32; j += 8)
    tile[ty + j][tx] = W[(size_t)(k0 + ty + j) * Nd + n0 + tx];
  __syncthreads();
  #pragma unroll
  for (int j = 0; j < 32; j += 8)
    Wt[(size_t)(n0 + ty + j) * Kd + k0 + tx] = __float2bfloat16(tile[tx][ty + j]);
}

// ---- LayerNorm (ddof=1): fp32 [8192][1024] -> bf16 ----
__global__ __launch_bounds__(256) void ln_kernel(const float* __restrict__ x,
                                                 const float* __restrict__ sc,
                                                 const float* __restrict__ bi,
                                                 bf16* __restrict__ out) {
  int row = blockIdx.x, tid = threadIdx.x;
  const float4* xr = (const float4*)(x + (size_t)row * EMB);
  float4 v = xr[tid];
  float s  = v.x + v.y + v.z + v.w;
  float s2 = v.x * v.x + v.y * v.y + v.z * v.z + v.w * v.w;
  #pragma unroll
  for (int off = 1; off < 64; off <<= 1) {
    s  += __shfl_xor(s, off);
    s2 += __shfl_xor(s2, off);
  }
  __shared__ float red[8];
  int wv = tid >> 6;
  if ((tid & 63) == 0) { red[wv] = s; red[4 + wv] = s2; }
  __syncthreads();
  s  = red[0] + red[1] + red[2] + red[3];
  s2 = red[4] + red[5] + red[6] + red[7];
  float mean = s * (1.0f / EMB);
  float var  = (s2 - (float)EMB * mean * mean) * (1.0f / (EMB - 1));
  float rstd = rsqrtf(var + 1e-5f);
  float4 scv = ((const float4*)sc)[tid];
  float4 biv = ((const float4*)bi)[tid];
  ushort4 o;
  o.x = f2bu((v.x - mean) * rstd * scv.x + biv.x);
  o.y = f2bu((v.y - mean) * rstd * scv.y + biv.y);
  o.z = f2bu((v.z - mean) * rstd * scv.z + biv.z);
  o.w = f2bu((v.w - mean) * rstd * scv.w + biv.w);
  ((ushort4*)(out + (size_t)row * EMB))[tid] = o;
}

// ---- 128x128 2-phase GEMM, catalog "minimum 2-phase" (T2+T3/T4-lite+T5):
// C[M][Nd] = A[M][Kd] * Bt[Nd][Kd]^T. 256 thr = 4 waves (2x2), BK=32,
// double-buffered LDS. Per K-step: barrier; STAGE(t+1) issue; vmcnt(4)
// (waits tile t only, t+1 stays in flight); ds_read frags (swizzled,
// rule 21 both-sides); setprio(1) 16 MFMA setprio(0). One barrier/step.
// MODE 3: fp32 out = C+bias+resid   MODE 4: bf16 out = gelu(C+bias)
// MODE 6: fused QKV scatter via blockIdx.z (0=q scaled, 1=k, 2=vT)
template<int Kd, int MODE>
__global__ __launch_bounds__(256, 4) void gemm2_kernel(
    const bf16* __restrict__ A, const bf16* __restrict__ Bt,
    const float* __restrict__ bias, const float* __restrict__ resid,
    void* __restrict__ outp) {
  constexpr int NT = Kd / 32;
  __shared__ __align__(16) bf16 As[2][128 * 32];
  __shared__ __align__(16) bf16 Bs[2][128 * 32];
  const int tid = threadIdx.x;
  const int lane = tid & 63, wave = tid >> 6;
  const int lo = lane & 15, hi = lane >> 4;
  const int wr = wave >> 1, wc = wave & 1;
  const int m0 = blockIdx.x * 128, n0 = blockIdx.y * 128;

  const bf16* Bt2 = Bt;
  if constexpr (MODE == 6) Bt2 = Bt + ((size_t)blockIdx.z << 20);
  const bf16* Ab = A   + (size_t)m0 * Kd;
  const bf16* Bb = Bt2 + (size_t)n0 * Kd;

  // LDS chunk (row, s) holds G(row, s ^ (row&3)); read col hi at slot
  // hi ^ (row&3). gll dest stays linear (rule 21: swizzle the SOURCE).
  auto STAGE = [&](int t, int b) {
    #pragma unroll
    for (int s = 0; s < 2; ++s) {
      const int c = tid + s * 256;
      const int row = c >> 2, slot = (c & 3) ^ (row & 3);
      gll16(Ab + (size_t)row * Kd + t * 32 + slot * 8, As[b] + c * 8);
      gll16(Bb + (size_t)row * Kd + t * 32 + slot * 8, Bs[b] + c * 8);
    }
  };

  floatx4 acc[4][4];
  #pragma unroll
  for (int i = 0; i < 4; i++)
    #pragma unroll
    for (int j = 0; j < 4; j++)
      #pragma unroll
      for (int r = 0; r < 4; r++) acc[i][j][r] = 0.0f;

  STAGE(0, 0);

  for (int t = 0; t < NT; ++t) {
    const int bb = t & 1;
    // top barrier: all waves consumed buf[bb^1] (MFMA data-dep drained lgkm)
    __builtin_amdgcn_s_barrier();
    __builtin_amdgcn_sched_barrier(0);
    if (t + 1 < NT) {
      STAGE(t + 1, bb ^ 1);
      asm volatile("s_waitcnt vmcnt(4)" ::: "memory");  // tile t landed; t+1 in flight
    } else {
      asm volatile("s_waitcnt vmcnt(0)" ::: "memory");
    }
    __builtin_amdgcn_sched_barrier(0);
    short8 af[4], bfr[4];
    #pragma unroll
    for (int i = 0; i < 4; i++) {
      const int row = wr * 64 + i * 16 + lo;
      af[i] = *(const short8*)&As[bb][row * 32 + ((hi ^ (lo & 3)) * 8)];
    }
    #pragma unroll
    for (int j = 0; j < 4; j++) {
      const int row = wc * 64 + j * 16 + lo;
      bfr[j] = *(const short8*)&Bs[bb][row * 32 + ((hi ^ (lo & 3)) * 8)];
    }
    __builtin_amdgcn_s_setprio(1);
    #pragma unroll
    for (int i = 0; i < 4; i++)
      #pragma unroll
      for (int j = 0; j < 4; j++)
        acc[i][j] = __builtin_amdgcn_mfma_f32_16x16x32_bf16(af[i], bfr[j], acc[i][j], 0, 0, 0);
    __builtin_amdgcn_s_setprio(0);
  }

  #pragma unroll
  for (int i = 0; i < 4; i++) {
    #pragma unroll
    for (int j = 0; j < 4; j++) {
      const int mb = m0 + wr * 64 + i * 16 + hi * 4;   // 4 consecutive m = mb+r
      const int n  = n0 + wc * 64 + j * 16 + lo;
      if constexpr (MODE == 6) {
        const int z = blockIdx.z;
        const int bx = mb >> 11, hhh = n >> 6, d = n & 63;
        bf16* ob = (bf16*)outp + ((size_t)z << 23);
        if (z == 2) {
          // v transposed [b,h,d,s]: pack 4 consecutive s into one 8B store
          ushort4 pk;
          pk.x = f2bu(acc[i][j][0]); pk.y = f2bu(acc[i][j][1]);
          pk.z = f2bu(acc[i][j][2]); pk.w = f2bu(acc[i][j][3]);
          *(ushort4*)&ob[((size_t)(bx * HEADS + hhh) * HDIM + d) * SEQ + (mb & 2047)] = pk;
        } else {
          const float sc = (z == 0) ? 0.125f : 1.0f;   // fold softmax scale into q
          #pragma unroll
          for (int r = 0; r < 4; r++) {
            const int ss = (mb + r) & 2047;
            ob[((size_t)(bx * HEADS + hhh) * SEQ + ss) * HDIM + d] =
                __float2bfloat16(acc[i][j][r] * sc);
          }
        }
      } else if constexpr (MODE == 3) {
        #pragma unroll
        for (int r = 0; r < 4; r++) {
          const int m = mb + r;
          ((float*)outp)[(size_t)m * EMB + n] =
              acc[i][j][r] + bias[n] + resid[(size_t)m * EMB + n];
        }
      } else if constexpr (MODE == 4) {
        #pragma unroll
        for (int r = 0; r < 4; r++)
          ((bf16*)outp)[(size_t)(mb + r) * FFDIM + n] =
              __float2bfloat16(gelu_f(acc[i][j][r] + bias[n]));
      }
    }
  }
}

// ---- causal flash attention, staged + double-buffered (round-2 + T5) ----
__global__ __launch_bounds__(256, 2) void attn_kernel(
    const bf16* __restrict__ q, const bf16* __restrict__ k,
    const bf16* __restrict__ vt, bf16* __restrict__ ctx) {
  __shared__ __align__(16) char KVs[2][2][64 * 128];
  __shared__ __align__(16) char Pls[4][4096];
  const int bh = blockIdx.x, qt = blockIdx.y;
  const int tid = threadIdx.x;
  const int wave = tid >> 6, lane = tid & 63;
  const int lo = lane & 15, hi = lane >> 4;
  const int lo7 = lo & 7;
  const int q0 = qt * 128;
  const int q0w = q0 + wave * 32;
  const int qmax = q0w + 31;

  const bf16* qp = q  + ((size_t)bh * SEQ + q0w) * HDIM;
  const bf16* kp = k  + (size_t)bh * SEQ * HDIM;
  const bf16* vp = vt + (size_t)bh * HDIM * SEQ;

  short8 qf[2][2];
  #pragma unroll
  for (int m = 0; m < 2; m++)
    #pragma unroll
    for (int kk = 0; kk < 2; kk++)
      qf[m][kk] = *(const short8*)&qp[(size_t)(m * 16 + lo) * HDIM + kk * 32 + hi * 8];

  float m_run[2] = {-1e30f, -1e30f};
  float l_run[2] = {0.0f, 0.0f};
  floatx4 o[4][2];
  #pragma unroll
  for (int df = 0; df < 4; df++)
    #pragma unroll
    for (int m = 0; m < 2; m++)
      #pragma unroll
      for (int r = 0; r < 4; r++) o[df][m][r] = 0.0f;

  const int nt = 2 * qt + 2;

  const int c0 = tid, c1 = tid + 256;
  const int r0 = c0 >> 3, s0 = (c0 & 7) ^ (r0 & 7);
  const int r1 = c1 >> 3, s1 = (c1 & 7) ^ (r1 & 7);

  gll16(kp + (size_t)r0 * HDIM + s0 * 8, (bf16*)&KVs[0][0][c0 * 16]);
  gll16(vp + (size_t)r0 * SEQ + s0 * 8,  (bf16*)&KVs[0][1][c0 * 16]);
  gll16(kp + (size_t)r1 * HDIM + s1 * 8, (bf16*)&KVs[0][0][c1 * 16]);
  gll16(vp + (size_t)r1 * SEQ + s1 * 8,  (bf16*)&KVs[0][1][c1 * 16]);

  for (int t = 0; t < nt; ++t) {
    const int buf = t & 1;
    const int k0 = t * KVB;
    if (t + 1 < nt) {
      const int kn = k0 + KVB;
      gll16(kp + (size_t)(kn + r0) * HDIM + s0 * 8, (bf16*)&KVs[buf ^ 1][0][c0 * 16]);
      gll16(vp + (size_t)r0 * SEQ + kn + s0 * 8,    (bf16*)&KVs[buf ^ 1][1][c0 * 16]);
      gll16(kp + (size_t)(kn + r1) * HDIM + s1 * 8, (bf16*)&KVs[buf ^ 1][0][c1 * 16]);
      gll16(vp + (size_t)r1 * SEQ + kn + s1 * 8,    (bf16*)&KVs[buf ^ 1][1][c1 * 16]);
      asm volatile("s_waitcnt vmcnt(4)" ::: "memory");
    } else {
      asm volatile("s_waitcnt vmcnt(0)" ::: "memory");
    }
    __builtin_amdgcn_s_barrier();
    __builtin_amdgcn_sched_barrier(0);

    if (k0 <= qmax) {
      const char* Kb = KVs[buf][0];
      const char* Vb = KVs[buf][1];
      floatx4 sfr[4][2];
      __builtin_amdgcn_s_setprio(1);
      #pragma unroll
      for (int kf = 0; kf < 4; kf++) {
        const int rowb = (kf * 16 + lo) * 128;
        short8 kf0 = *(const short8*)(Kb + rowb + (( 0 + hi * 16) ^ (lo7 << 4)));
        short8 kf1 = *(const short8*)(Kb + rowb + ((64 + hi * 16) ^ (lo7 << 4)));
        #pragma unroll
        for (int m = 0; m < 2; m++) {
          floatx4 z = {0.0f, 0.0f, 0.0f, 0.0f};
          z = __builtin_amdgcn_mfma_f32_16x16x32_bf16(kf0, qf[m][0], z, 0, 0, 0);
          z = __builtin_amdgcn_mfma_f32_16x16x32_bf16(kf1, qf[m][1], z, 0, 0, 0);
          sfr[kf][m] = z;
        }
      }
      __builtin_amdgcn_s_setprio(0);
      if (k0 + KVB - 1 > q0w) {
        #pragma unroll
        for (int m = 0; m < 2; m++) {
          const int qg = q0w + m * 16 + lo;
          #pragma unroll
          for (int kf = 0; kf < 4; kf++)
            #pragma unroll
            for (int r = 0; r < 4; r++) {
              const int key = k0 + kf * 16 + hi * 4 + r;
              if (key > qg) sfr[kf][m][r] = -1e30f;
            }
        }
      }
      float alpha[2];
      #pragma unroll
      for (int m = 0; m < 2; m++) {
        float tmax = -1e30f;
        #pragma unroll
        for (int kf = 0; kf < 4; kf++)
          #pragma unroll
          for (int r = 0; r < 4; r++) tmax = fmaxf(tmax, sfr[kf][m][r]);
        tmax = fmaxf(tmax, __shfl_xor(tmax, 16));
        tmax = fmaxf(tmax, __shfl_xor(tmax, 32));
        const float mn = fmaxf(m_run[m], tmax);
        alpha[m] = __expf(m_run[m] - mn);
        m_run[m] = mn;
        float ps = 0.0f;
        const int prow = (m * 16 + lo) * 128;
        #pragma unroll
        for (int kf = 0; kf < 4; kf++) {
          float p0 = __expf(sfr[kf][m][0] - mn);
          float p1 = __expf(sfr[kf][m][1] - mn);
          float p2 = __expf(sfr[kf][m][2] - mn);
          float p3 = __expf(sfr[kf][m][3] - mn);
          ps += (p0 + p1) + (p2 + p3);
          ushort4 pk;
          pk.x = f2bu(p0); pk.y = f2bu(p1); pk.z = f2bu(p2); pk.w = f2bu(p3);
          *(ushort4*)(Pls[wave] + prow + ((kf * 32 + hi * 8) ^ (lo7 << 4))) = pk;
        }
        ps += __shfl_xor(ps, 16);
        ps += __shfl_xor(ps, 32);
        l_run[m] = l_run[m] * alpha[m] + ps;
      }
      asm volatile("s_waitcnt lgkmcnt(0)" ::: "memory");
      __builtin_amdgcn_sched_barrier(0);
      short8 pa[2][2];
      #pragma unroll
      for (int m = 0; m < 2; m++)
        #pragma unroll
        for (int kk2 = 0; kk2 < 2; kk2++)
          pa[m][kk2] = *(const short8*)(Pls[wave] + (m * 16 + lo) * 128 +
                                        ((kk2 * 64 + hi * 16) ^ (lo7 << 4)));
      float ar[2][4];
      #pragma unroll
      for (int m = 0; m < 2; m++)
        #pragma unroll
        for (int r = 0; r < 4; r++) ar[m][r] = __shfl(alpha[m], hi * 4 + r);
      #pragma unroll
      for (int df = 0; df < 4; df++)
        #pragma unroll
        for (int m = 0; m < 2; m++)
          #pragma unroll
          for (int r = 0; r < 4; r++) o[df][m][r] *= ar[m][r];
      __builtin_amdgcn_s_setprio(1);
      #pragma unroll
      for (int df = 0; df < 4; df++) {
        const int rowb = (df * 16 + lo) * 128;
        short8 vf0 = *(const short8*)(Vb + rowb + (( 0 + hi * 16) ^ (lo7 << 4)));
        short8 vf1 = *(const short8*)(Vb + rowb + ((64 + hi * 16) ^ (lo7 << 4)));
        #pragma unroll
        for (int m = 0; m < 2; m++) {
          o[df][m] = __builtin_amdgcn_mfma_f32_16x16x32_bf16(pa[m][0], vf0, o[df][m], 0, 0, 0);
          o[df][m] = __builtin_amdgcn_mfma_f32_16x16x32_bf16(pa[m][1], vf1, o[df][m], 0, 0, 0);
        }
      }
      __builtin_amdgcn_s_setprio(0);
    }
    __builtin_amdgcn_s_barrier();
    __builtin_amdgcn_sched_barrier(0);
  }

  const int b = bh >> 4, hh = bh & 15;
  #pragma unroll
  for (int m = 0; m < 2; m++) {
    float lr[4];
    #pragma unroll
    for (int r = 0; r < 4; r++) lr[r] = __shfl(l_run[m], hi * 4 + r);
    #pragma unroll
    for (int df = 0; df < 4; df++)
      #pragma unroll
      for (int r = 0; r < 4; r++) {
        const int srow = q0w + m * 16 + hi * 4 + r;
        ctx[((size_t)(b * SEQ + srow)) * EMB + hh * HDIM + df * 16 + lo] =
            __float2bfloat16(o[df][m][r] / lr[r]);
      }
  }
}

extern "C" void kernel_launch(void* const* d_in, const int* in_sizes, int n_in,
                              void* d_out, int out_size, void* d_ws, size_t ws_size,
                              hipStream_t stream) {
  const float* x   = (const float*)d_in[0];
  const float* Wq  = (const float*)d_in[1];
  const float* Wk  = (const float*)d_in[2];
  const float* Wv  = (const float*)d_in[3];
  const float* Wo  = (const float*)d_in[4];
  const float* bo  = (const float*)d_in[5];
  const float* l1s = (const float*)d_in[6];
  const float* l1b = (const float*)d_in[7];
  const float* l2s = (const float*)d_in[8];
  const float* l2b = (const float*)d_in[9];
  const float* W1  = (const float*)d_in[10];
  const float* b1  = (const float*)d_in[11];
  const float* W2  = (const float*)d_in[12];
  const float* b2  = (const float*)d_in[13];
  float* out = (float*)d_out;

  char* ws = (char*)d_ws;
  bf16* hbuf   = (bf16*)(ws);
  bf16* qbuf   = (bf16*)(ws + ((size_t)16 << 20));
  bf16* kbuf   = (bf16*)(ws + ((size_t)32 << 20));
  bf16* vbuf   = (bf16*)(ws + ((size_t)48 << 20));
  bf16* ctxbuf = hbuf;
  bf16* gbuf   = (bf16*)(ws);
  bf16* h2buf  = (bf16*)(ws + ((size_t)64 << 20));
  bf16* WqT    = (bf16*)(ws + ((size_t)80 << 20));
  bf16* WkT    = WqT + (1u << 20);
  bf16* WvT    = WkT + (1u << 20);
  bf16* WoT    = WvT + (1u << 20);
  bf16* W1T    = WoT + (1u << 20);
  bf16* W2T    = W1T + (4u << 20);

  wconv_kernel<<<dim3(32, 32), 256, 0, stream>>>(Wq, WqT, 1024, 1024);
  wconv_kernel<<<dim3(32, 32), 256, 0, stream>>>(Wk, WkT, 1024, 1024);
  wconv_kernel<<<dim3(32, 32), 256, 0, stream>>>(Wv, WvT, 1024, 1024);
  wconv_kernel<<<dim3(32, 32), 256, 0, stream>>>(Wo, WoT, 1024, 1024);
  wconv_kernel<<<dim3(128, 32), 256, 0, stream>>>(W1, W1T, 1024, 4096);
  wconv_kernel<<<dim3(32, 128), 256, 0, stream>>>(W2, W2T, 4096, 1024);

  ln_kernel<<<8192, 256, 0, stream>>>(x, l1s, l1b, hbuf);

  // fused QKV: z=0 -> q (scaled), z=1 -> k, z=2 -> v transposed
  gemm2_kernel<1024, 6><<<dim3(64, 8, 3), 256, 0, stream>>>(
      hbuf, WqT, nullptr, nullptr, qbuf);

  attn_kernel<<<dim3(64, 16), 256, 0, stream>>>(qbuf, kbuf, vbuf, ctxbuf);

  // Wo + bias + residual (fp32 out)
  gemm2_kernel<1024, 3><<<dim3(64, 8), 256, 0, stream>>>(
      ctxbuf, WoT, bo, x, (void*)out);
  ln_kernel<<<8192, 256, 0, stream>>>(out, l2s, l2b, h2buf);
  // FF1: gelu
  gemm2_kernel<1024, 4><<<dim3(64, 32), 256, 0, stream>>>(
      h2buf, W1T, b1, nullptr, gbuf);
  // FF2: K=4096, bias + residual (fp32 out)
  gemm2_kernel<4096, 3><<<dim3(64, 8), 256, 0, stream>>>(
      gbuf, W2T, b2, out, (void*)out);
}

// Round 7
// 516.934 us; speedup vs baseline: 1.1502x; 1.0042x over previous
//
#include <hip/hip_runtime.h>
#include <hip/hip_bf16.h>
#include <math.h>

typedef __hip_bfloat16 bf16;
typedef __attribute__((ext_vector_type(8))) short short8;
typedef __attribute__((ext_vector_type(4))) float floatx4;

#define EMB   1024
#define SEQ   2048
#define BATCH 4
#define M_TOK 8192
#define HEADS 16
#define HDIM  64
#define FFDIM 4096
#define KVB   64

typedef __attribute__((address_space(3))) void lds_t;
typedef __attribute__((address_space(1))) void glob_t;

static __device__ __forceinline__ void gll16(const bf16* g, bf16* l) {
  __builtin_amdgcn_global_load_lds((const glob_t*)g, (lds_t*)l, 16, 0, 0);
}

static __device__ __forceinline__ unsigned short f2bu(float f) {
  union { __hip_bfloat16 h; unsigned short u; } cv;
  cv.h = __float2bfloat16(f);
  return cv.u;
}

// fast tanh-gelu: 0.5x(1+tanh(y)) == x / (1 + e^{-2y}); one v_exp_f32.
// y<0 large: e^{-2y}->inf -> 0 (correct); y>0 large: ->x (correct).
static __device__ __forceinline__ float gelu_f(float x) {
  float y = 0.7978845608028654f * (x + 0.044715f * x * x * x);
  return x / (1.0f + __expf(-2.0f * y));
}

// ---- merged weight convert+transpose for all 6 weights (1 launch) ----
// W fp32 [Kd][Nd] -> Wt bf16 [Nd][Kd], 32x32 tiles.
// grid: [0,4096) Wq/Wk/Wv/Wo (1024 tiles each); [4096,8192) W1; [8192,12288) W2
__global__ __launch_bounds__(256) void wconv_all_kernel(
    const float* __restrict__ Wq, const float* __restrict__ Wk,
    const float* __restrict__ Wv, const float* __restrict__ Wo,
    const float* __restrict__ W1, const float* __restrict__ W2,
    bf16* WqT, bf16* WkT, bf16* WvT, bf16* WoT, bf16* W1T, bf16* W2T) {
  const int idx = blockIdx.x;
  const float* W; bf16* Wt; int Kd, Nd, rem;
  if (idx < 4096) {
    const int m = idx >> 10; rem = idx & 1023; Kd = 1024; Nd = 1024;
    W  = (m == 0) ? Wq  : (m == 1) ? Wk  : (m == 2) ? Wv  : Wo;
    Wt = (m == 0) ? WqT : (m == 1) ? WkT : (m == 2) ? WvT : WoT;
  } else if (idx < 8192) {
    rem = idx - 4096; Kd = 1024; Nd = 4096; W = W1; Wt = W1T;
  } else {
    rem = idx - 8192; Kd = 4096; Nd = 1024; W = W2; Wt = W2T;
  }
  const int nb = Nd >> 5;
  const int n0 = (rem % nb) * 32, k0 = (rem / nb) * 32;
  __shared__ float tile[32][33];
  const int tx = threadIdx.x & 31, ty = threadIdx.x >> 5;
  #pragma unroll
  for (int j = 0; j < 32; j += 8)
    tile[ty + j][tx] = W[(size_t)(k0 + ty + j) * Nd + n0 + tx];
  __syncthreads();
  #pragma unroll
  for (int j = 0; j < 32; j += 8)
    Wt[(size_t)(n0 + ty + j) * Kd + k0 + tx] = __float2bfloat16(tile[tx][ty + j]);
}

// ---- LayerNorm (ddof=1): fp32 [8192][1024] -> bf16 ----
__global__ __launch_bounds__(256) void ln_kernel(const float* __restrict__ x,
                                                 const float* __restrict__ sc,
                                                 const float* __restrict__ bi,
                                                 bf16* __restrict__ out) {
  int row = blockIdx.x, tid = threadIdx.x;
  const float4* xr = (const float4*)(x + (size_t)row * EMB);
  float4 v = xr[tid];
  float s  = v.x + v.y + v.z + v.w;
  float s2 = v.x * v.x + v.y * v.y + v.z * v.z + v.w * v.w;
  #pragma unroll
  for (int off = 1; off < 64; off <<= 1) {
    s  += __shfl_xor(s, off);
    s2 += __shfl_xor(s2, off);
  }
  __shared__ float red[8];
  int wv = tid >> 6;
  if ((tid & 63) == 0) { red[wv] = s; red[4 + wv] = s2; }
  __syncthreads();
  s  = red[0] + red[1] + red[2] + red[3];
  s2 = red[4] + red[5] + red[6] + red[7];
  float mean = s * (1.0f / EMB);
  float var  = (s2 - (float)EMB * mean * mean) * (1.0f / (EMB - 1));
  float rstd = rsqrtf(var + 1e-5f);
  float4 scv = ((const float4*)sc)[tid];
  float4 biv = ((const float4*)bi)[tid];
  ushort4 o;
  o.x = f2bu((v.x - mean) * rstd * scv.x + biv.x);
  o.y = f2bu((v.y - mean) * rstd * scv.y + biv.y);
  o.z = f2bu((v.z - mean) * rstd * scv.z + biv.z);
  o.w = f2bu((v.w - mean) * rstd * scv.w + biv.w);
  ((ushort4*)(out + (size_t)row * EMB))[tid] = o;
}

// ---- 128x128 2-phase GEMM (T2 fixed + T3/T4-lite + T5):
// C[M][Nd] = A[M][Kd] * Bt[Nd][Kd]^T. 256 thr = 4 waves (2x2), BK=32,
// double-buffered LDS, counted vmcnt(4), one barrier/K-step.
// 64B LDS rows: bank-quad = (4*row + slot) mod 8 -> correct XOR key is
// (row>>1)&3 (NOT row&3; that double-counts row bit0 -> 4-way conflict,
// measured 8.4M extra cycles in r6). Both-sides: pre-swizzled gll SOURCE
// (linear dest) + same key on ds_read slot. Staging via 4 persistent
// pointers bumped +32 elems/step (cuts addr VALU).
// MODE 3: fp32 out = C+bias+resid   MODE 4: bf16 out = gelu(C+bias)
// MODE 6: fused QKV scatter via blockIdx.z (0=q scaled, 1=k, 2=vT)
template<int Kd, int MODE>
__global__ __launch_bounds__(256, 4) void gemm2_kernel(
    const bf16* __restrict__ A, const bf16* __restrict__ Bt,
    const float* __restrict__ bias, const float* __restrict__ resid,
    void* __restrict__ outp) {
  constexpr int NT = Kd / 32;
  __shared__ __align__(16) bf16 As[2][128 * 32];
  __shared__ __align__(16) bf16 Bs[2][128 * 32];
  const int tid = threadIdx.x;
  const int lane = tid & 63, wave = tid >> 6;
  const int lo = lane & 15, hi = lane >> 4;
  const int wr = wave >> 1, wc = wave & 1;
  const int m0 = blockIdx.x * 128, n0 = blockIdx.y * 128;

  const bf16* Bt2 = Bt;
  if constexpr (MODE == 6) Bt2 = Bt + ((size_t)blockIdx.z << 20);
  const bf16* Ab = A   + (size_t)m0 * Kd;
  const bf16* Bb = Bt2 + (size_t)n0 * Kd;

  // staging: chunk c -> row c>>2, LDS slot c&3 (linear dest); source slot
  // (c&3) ^ ((row>>1)&3). For both c=tid and c=tid+256 the key equals
  // (tid>>3)&3 (row bit shift absorbs +256).
  const int c0 = tid, c1 = tid + 256;
  const int ssw = (tid & 3) ^ ((tid >> 3) & 3);
  const bf16* pa0 = Ab + (size_t)(c0 >> 2) * Kd + ssw * 8;
  const bf16* pa1 = Ab + (size_t)(c1 >> 2) * Kd + ssw * 8;
  const bf16* pb0 = Bb + (size_t)(c0 >> 2) * Kd + ssw * 8;
  const bf16* pb1 = Bb + (size_t)(c1 >> 2) * Kd + ssw * 8;

  // fragment-read slot key: row = base16 + lo -> (row>>1)&3 = (lo>>1)&3,
  // lane-constant. Byte-slot read = hi ^ ((lo>>1)&3).
  const int koff = (hi ^ ((lo >> 1) & 3)) * 8;

  floatx4 acc[4][4];
  #pragma unroll
  for (int i = 0; i < 4; i++)
    #pragma unroll
    for (int j = 0; j < 4; j++)
      #pragma unroll
      for (int r = 0; r < 4; r++) acc[i][j][r] = 0.0f;

  // prologue: stage tile 0 into buf 0
  gll16(pa0, As[0] + c0 * 8); gll16(pb0, Bs[0] + c0 * 8);
  gll16(pa1, As[0] + c1 * 8); gll16(pb1, Bs[0] + c1 * 8);
  pa0 += 32; pb0 += 32; pa1 += 32; pb1 += 32;

  auto KSTEP = [&](int bb, bool stage_next) {
    __builtin_amdgcn_s_barrier();           // buf[bb^1] fully consumed
    __builtin_amdgcn_sched_barrier(0);
    if (stage_next) {
      gll16(pa0, As[bb ^ 1] + c0 * 8); gll16(pb0, Bs[bb ^ 1] + c0 * 8);
      gll16(pa1, As[bb ^ 1] + c1 * 8); gll16(pb1, Bs[bb ^ 1] + c1 * 8);
      pa0 += 32; pb0 += 32; pa1 += 32; pb1 += 32;
      asm volatile("s_waitcnt vmcnt(4)" ::: "memory");  // tile bb landed
    } else {
      asm volatile("s_waitcnt vmcnt(0)" ::: "memory");
    }
    __builtin_amdgcn_sched_barrier(0);
    short8 af[4], bfr[4];
    #pragma unroll
    for (int i = 0; i < 4; i++)
      af[i] = *(const short8*)&As[bb][(wr * 64 + i * 16 + lo) * 32 + koff];
    #pragma unroll
    for (int j = 0; j < 4; j++)
      bfr[j] = *(const short8*)&Bs[bb][(wc * 64 + j * 16 + lo) * 32 + koff];
    __builtin_amdgcn_s_setprio(1);
    #pragma unroll
    for (int i = 0; i < 4; i++)
      #pragma unroll
      for (int j = 0; j < 4; j++)
        acc[i][j] = __builtin_amdgcn_mfma_f32_16x16x32_bf16(af[i], bfr[j], acc[i][j], 0, 0, 0);
    __builtin_amdgcn_s_setprio(0);
  };

  for (int t = 0; t < NT; t += 2) {
    KSTEP(0, t + 1 < NT);
    KSTEP(1, t + 2 < NT);
  }

  #pragma unroll
  for (int i = 0; i < 4; i++) {
    #pragma unroll
    for (int j = 0; j < 4; j++) {
      const int mb = m0 + wr * 64 + i * 16 + hi * 4;   // 4 consecutive m = mb+r
      const int n  = n0 + wc * 64 + j * 16 + lo;
      if constexpr (MODE == 6) {
        const int z = blockIdx.z;
        const int bx = mb >> 11, hhh = n >> 6, d = n & 63;
        bf16* ob = (bf16*)outp + ((size_t)z << 23);
        if (z == 2) {
          // v transposed [b,h,d,s]: pack 4 consecutive s into one 8B store
          ushort4 pk;
          pk.x = f2bu(acc[i][j][0]); pk.y = f2bu(acc[i][j][1]);
          pk.z = f2bu(acc[i][j][2]); pk.w = f2bu(acc[i][j][3]);
          *(ushort4*)&ob[((size_t)(bx * HEADS + hhh) * HDIM + d) * SEQ + (mb & 2047)] = pk;
        } else {
          const float sc = (z == 0) ? 0.125f : 1.0f;   // fold softmax scale into q
          #pragma unroll
          for (int r = 0; r < 4; r++) {
            const int ss = (mb + r) & 2047;
            ob[((size_t)(bx * HEADS + hhh) * SEQ + ss) * HDIM + d] =
                __float2bfloat16(acc[i][j][r] * sc);
          }
        }
      } else if constexpr (MODE == 3) {
        #pragma unroll
        for (int r = 0; r < 4; r++) {
          const int m = mb + r;
          ((float*)outp)[(size_t)m * EMB + n] =
              acc[i][j][r] + bias[n] + resid[(size_t)m * EMB + n];
        }
      } else if constexpr (MODE == 4) {
        #pragma unroll
        for (int r = 0; r < 4; r++)
          ((bf16*)outp)[(size_t)(mb + r) * FFDIM + n] =
              __float2bfloat16(gelu_f(acc[i][j][r] + bias[n]));
      }
    }
  }
}

// ---- causal flash attention, staged + double-buffered (round-2 + T5) ----
// 128B LDS rows: quad = slot ^ (row&7) -> the (row&7) key IS correct here.
__global__ __launch_bounds__(256, 2) void attn_kernel(
    const bf16* __restrict__ q, const bf16* __restrict__ k,
    const bf16* __restrict__ vt, bf16* __restrict__ ctx) {
  __shared__ __align__(16) char KVs[2][2][64 * 128];
  __shared__ __align__(16) char Pls[4][4096];
  const int bh = blockIdx.x, qt = blockIdx.y;
  const int tid = threadIdx.x;
  const int wave = tid >> 6, lane = tid & 63;
  const int lo = lane & 15, hi = lane >> 4;
  const int lo7 = lo & 7;
  const int q0 = qt * 128;
  const int q0w = q0 + wave * 32;
  const int qmax = q0w + 31;

  const bf16* qp = q  + ((size_t)bh * SEQ + q0w) * HDIM;
  const bf16* kp = k  + (size_t)bh * SEQ * HDIM;
  const bf16* vp = vt + (size_t)bh * HDIM * SEQ;

  short8 qf[2][2];
  #pragma unroll
  for (int m = 0; m < 2; m++)
    #pragma unroll
    for (int kk = 0; kk < 2; kk++)
      qf[m][kk] = *(const short8*)&qp[(size_t)(m * 16 + lo) * HDIM + kk * 32 + hi * 8];

  float m_run[2] = {-1e30f, -1e30f};
  float l_run[2] = {0.0f, 0.0f};
  floatx4 o[4][2];
  #pragma unroll
  for (int df = 0; df < 4; df++)
    #pragma unroll
    for (int m = 0; m < 2; m++)
      #pragma unroll
      for (int r = 0; r < 4; r++) o[df][m][r] = 0.0f;

  const int nt = 2 * qt + 2;

  const int c0 = tid, c1 = tid + 256;
  const int r0 = c0 >> 3, s0 = (c0 & 7) ^ (r0 & 7);
  const int r1 = c1 >> 3, s1 = (c1 & 7) ^ (r1 & 7);

  gll16(kp + (size_t)r0 * HDIM + s0 * 8, (bf16*)&KVs[0][0][c0 * 16]);
  gll16(vp + (size_t)r0 * SEQ + s0 * 8,  (bf16*)&KVs[0][1][c0 * 16]);
  gll16(kp + (size_t)r1 * HDIM + s1 * 8, (bf16*)&KVs[0][0][c1 * 16]);
  gll16(vp + (size_t)r1 * SEQ + s1 * 8,  (bf16*)&KVs[0][1][c1 * 16]);

  for (int t = 0; t < nt; ++t) {
    const int buf = t & 1;
    const int k0 = t * KVB;
    if (t + 1 < nt) {
      const int kn = k0 + KVB;
      gll16(kp + (size_t)(kn + r0) * HDIM + s0 * 8, (bf16*)&KVs[buf ^ 1][0][c0 * 16]);
      gll16(vp + (size_t)r0 * SEQ + kn + s0 * 8,    (bf16*)&KVs[buf ^ 1][1][c0 * 16]);
      gll16(kp + (size_t)(kn + r1) * HDIM + s1 * 8, (bf16*)&KVs[buf ^ 1][0][c1 * 16]);
      gll16(vp + (size_t)r1 * SEQ + kn + s1 * 8,    (bf16*)&KVs[buf ^ 1][1][c1 * 16]);
      asm volatile("s_waitcnt vmcnt(4)" ::: "memory");
    } else {
      asm volatile("s_waitcnt vmcnt(0)" ::: "memory");
    }
    __builtin_amdgcn_s_barrier();
    __builtin_amdgcn_sched_barrier(0);

    if (k0 <= qmax) {
      const char* Kb = KVs[buf][0];
      const char* Vb = KVs[buf][1];
      floatx4 sfr[4][2];
      __builtin_amdgcn_s_setprio(1);
      #pragma unroll
      for (int kf = 0; kf < 4; kf++) {
        const int rowb = (kf * 16 + lo) * 128;
        short8 kf0 = *(const short8*)(Kb + rowb + (( 0 + hi * 16) ^ (lo7 << 4)));
        short8 kf1 = *(const short8*)(Kb + rowb + ((64 + hi * 16) ^ (lo7 << 4)));
        #pragma unroll
        for (int m = 0; m < 2; m++) {
          floatx4 z = {0.0f, 0.0f, 0.0f, 0.0f};
          z = __builtin_amdgcn_mfma_f32_16x16x32_bf16(kf0, qf[m][0], z, 0, 0, 0);
          z = __builtin_amdgcn_mfma_f32_16x16x32_bf16(kf1, qf[m][1], z, 0, 0, 0);
          sfr[kf][m] = z;
        }
      }
      __builtin_amdgcn_s_setprio(0);
      if (k0 + KVB - 1 > q0w) {
        #pragma unroll
        for (int m = 0; m < 2; m++) {
          const int qg = q0w + m * 16 + lo;
          #pragma unroll
          for (int kf = 0; kf < 4; kf++)
            #pragma unroll
            for (int r = 0; r < 4; r++) {
              const int key = k0 + kf * 16 + hi * 4 + r;
              if (key > qg) sfr[kf][m][r] = -1e30f;
            }
        }
      }
      float alpha[2];
      #pragma unroll
      for (int m = 0; m < 2; m++) {
        float tmax = -1e30f;
        #pragma unroll
        for (int kf = 0; kf < 4; kf++)
          #pragma unroll
          for (int r = 0; r < 4; r++) tmax = fmaxf(tmax, sfr[kf][m][r]);
        tmax = fmaxf(tmax, __shfl_xor(tmax, 16));
        tmax = fmaxf(tmax, __shfl_xor(tmax, 32));
        const float mn = fmaxf(m_run[m], tmax);
        alpha[m] = __expf(m_run[m] - mn);
        m_run[m] = mn;
        float ps = 0.0f;
        const int prow = (m * 16 + lo) * 128;
        #pragma unroll
        for (int kf = 0; kf < 4; kf++) {
          float p0 = __expf(sfr[kf][m][0] - mn);
          float p1 = __expf(sfr[kf][m][1] - mn);
          float p2 = __expf(sfr[kf][m][2] - mn);
          float p3 = __expf(sfr[kf][m][3] - mn);
          ps += (p0 + p1) + (p2 + p3);
          ushort4 pk;
          pk.x = f2bu(p0); pk.y = f2bu(p1); pk.z = f2bu(p2); pk.w = f2bu(p3);
          *(ushort4*)(Pls[wave] + prow + ((kf * 32 + hi * 8) ^ (lo7 << 4))) = pk;
        }
        ps += __shfl_xor(ps, 16);
        ps += __shfl_xor(ps, 32);
        l_run[m] = l_run[m] * alpha[m] + ps;
      }
      asm volatile("s_waitcnt lgkmcnt(0)" ::: "memory");
      __builtin_amdgcn_sched_barrier(0);
      short8 pa[2][2];
      #pragma unroll
      for (int m = 0; m < 2; m++)
        #pragma unroll
        for (int kk2 = 0; kk2 < 2; kk2++)
          pa[m][kk2] = *(const short8*)(Pls[wave] + (m * 16 + lo) * 128 +
                                        ((kk2 * 64 + hi * 16) ^ (lo7 << 4)));
      float ar[2][4];
      #pragma unroll
      for (int m = 0; m < 2; m++)
        #pragma unroll
        for (int r = 0; r < 4; r++) ar[m][r] = __shfl(alpha[m], hi * 4 + r);
      #pragma unroll
      for (int df = 0; df < 4; df++)
        #pragma unroll
        for (int m = 0; m < 2; m++)
          #pragma unroll
          for (int r = 0; r < 4; r++) o[df][m][r] *= ar[m][r];
      __builtin_amdgcn_s_setprio(1);
      #pragma unroll
      for (int df = 0; df < 4; df++) {
        const int rowb = (df * 16 + lo) * 128;
        short8 vf0 = *(const short8*)(Vb + rowb + (( 0 + hi * 16) ^ (lo7 << 4)));
        short8 vf1 = *(const short8*)(Vb + rowb + ((64 + hi * 16) ^ (lo7 << 4)));
        #pragma unroll
        for (int m = 0; m < 2; m++) {
          o[df][m] = __builtin_amdgcn_mfma_f32_16x16x32_bf16(pa[m][0], vf0, o[df][m], 0, 0, 0);
          o[df][m] = __builtin_amdgcn_mfma_f32_16x16x32_bf16(pa[m][1], vf1, o[df][m], 0, 0, 0);
        }
      }
      __builtin_amdgcn_s_setprio(0);
    }
    __builtin_amdgcn_s_barrier();
    __builtin_amdgcn_sched_barrier(0);
  }

  const int b = bh >> 4, hh = bh & 15;
  #pragma unroll
  for (int m = 0; m < 2; m++) {
    float lr[4];
    #pragma unroll
    for (int r = 0; r < 4; r++) lr[r] = __shfl(l_run[m], hi * 4 + r);
    #pragma unroll
    for (int df = 0; df < 4; df++)
      #pragma unroll
      for (int r = 0; r < 4; r++) {
        const int srow = q0w + m * 16 + hi * 4 + r;
        ctx[((size_t)(b * SEQ + srow)) * EMB + hh * HDIM + df * 16 + lo] =
            __float2bfloat16(o[df][m][r] / lr[r]);
      }
  }
}

extern "C" void kernel_launch(void* const* d_in, const int* in_sizes, int n_in,
                              void* d_out, int out_size, void* d_ws, size_t ws_size,
                              hipStream_t stream) {
  const float* x   = (const float*)d_in[0];
  const float* Wq  = (const float*)d_in[1];
  const float* Wk  = (const float*)d_in[2];
  const float* Wv  = (const float*)d_in[3];
  const float* Wo  = (const float*)d_in[4];
  const float* bo  = (const float*)d_in[5];
  const float* l1s = (const float*)d_in[6];
  const float* l1b = (const float*)d_in[7];
  const float* l2s = (const float*)d_in[8];
  const float* l2b = (const float*)d_in[9];
  const float* W1  = (const float*)d_in[10];
  const float* b1  = (const float*)d_in[11];
  const float* W2  = (const float*)d_in[12];
  const float* b2  = (const float*)d_in[13];
  float* out = (float*)d_out;

  char* ws = (char*)d_ws;
  bf16* hbuf   = (bf16*)(ws);
  bf16* qbuf   = (bf16*)(ws + ((size_t)16 << 20));
  bf16* kbuf   = (bf16*)(ws + ((size_t)32 << 20));
  bf16* vbuf   = (bf16*)(ws + ((size_t)48 << 20));
  bf16* ctxbuf = hbuf;
  bf16* gbuf   = (bf16*)(ws);
  bf16* h2buf  = (bf16*)(ws + ((size_t)64 << 20));
  bf16* WqT    = (bf16*)(ws + ((size_t)80 << 20));
  bf16* WkT    = WqT + (1u << 20);
  bf16* WvT    = WkT + (1u << 20);
  bf16* WoT    = WvT + (1u << 20);
  bf16* W1T    = WoT + (1u << 20);
  bf16* W2T    = W1T + (4u << 20);

  wconv_all_kernel<<<12288, 256, 0, stream>>>(Wq, Wk, Wv, Wo, W1, W2,
                                              WqT, WkT, WvT, WoT, W1T, W2T);

  ln_kernel<<<8192, 256, 0, stream>>>(x, l1s, l1b, hbuf);

  // fused QKV: z=0 -> q (scaled), z=1 -> k, z=2 -> v transposed
  gemm2_kernel<1024, 6><<<dim3(64, 8, 3), 256, 0, stream>>>(
      hbuf, WqT, nullptr, nullptr, qbuf);

  attn_kernel<<<dim3(64, 16), 256, 0, stream>>>(qbuf, kbuf, vbuf, ctxbuf);

  // Wo + bias + residual (fp32 out)
  gemm2_kernel<1024, 3><<<dim3(64, 8), 256, 0, stream>>>(
      ctxbuf, WoT, bo, x, (void*)out);
  ln_kernel<<<8192, 256, 0, stream>>>(out, l2s, l2b, h2buf);
  // FF1: gelu
  gemm2_kernel<1024, 4><<<dim3(64, 32), 256, 0, stream>>>(
      h2buf, W1T, b1, nullptr, gbuf);
  // FF2: K=4096, bias + residual (fp32 out)
  gemm2_kernel<4096, 3><<<dim3(64, 8), 256, 0, stream>>>(
      gbuf, W2T, b2, out, (void*)out);
}